// Round 1
// baseline (584.618 us; speedup 1.0000x reference)
//
#include <hip/hip_runtime.h>
#include <hip/hip_bf16.h>

#define Bc 4
#define Tc 2048
#define Dc 1024
#define Ec 4
#define WRc 128
#define Hc 4096
#define Mc (Bc*Tc)        // 8192
#define K1c (Dc+WRc)      // 1152
#define Pc (1+Ec)         // 5
#define ZDc (Pc*Dc)       // 5120
#define EPSc 1e-5f

typedef __attribute__((ext_vector_type(8))) short short8;
typedef __attribute__((ext_vector_type(4))) float f32x4;

__device__ __forceinline__ float wave_red_sum(float v) {
    #pragma unroll
    for (int o = 32; o > 0; o >>= 1) v += __shfl_down(v, o);
    return v;
}

__device__ __forceinline__ float gelu_tanh(float x) {
    const float c = 0.7978845608028654f;  // sqrt(2/pi)
    float x3 = x * x * x;
    return 0.5f * x * (1.0f + tanhf(c * (x + 0.044715f * x3)));
}

// ---------------- transpose + cast f32 [R][C] -> bf16 [C][R] ----------------
__global__ __launch_bounds__(256) void transpose_cast_kernel(
    const float* __restrict__ src, __hip_bfloat16* __restrict__ dst, int R, int C) {
    __shared__ float tile[32][33];
    int c0 = blockIdx.x * 32, r0 = blockIdx.y * 32;
    int tx = threadIdx.x, ty = threadIdx.y;
    #pragma unroll
    for (int i = ty; i < 32; i += 8)
        tile[i][tx] = src[(size_t)(r0 + i) * C + c0 + tx];
    __syncthreads();
    #pragma unroll
    for (int i = ty; i < 32; i += 8)
        dst[(size_t)(c0 + i) * R + r0 + tx] = __float2bfloat16(tile[tx][i]);
}

// ------------- fused concat(x, r_feat) + LayerNorm -> bf16 [M][1152] --------
__global__ __launch_bounds__(256) void fuse_ln_kernel(
    const float* __restrict__ x, const float* __restrict__ rf,
    const float* __restrict__ g, const float* __restrict__ b,
    __hip_bfloat16* __restrict__ aln) {
    int row = blockIdx.x;
    int tid = threadIdx.x, lane = tid & 63, wave = tid >> 6;
    const float* xr = x + (size_t)row * Dc;
    const float* rr = rf + (size_t)row * WRc;

    float v[5];
    float s = 0.f, s2 = 0.f;
    #pragma unroll
    for (int i = 0; i < 4; i++) {          // idx 0..1023 -> x
        int idx = tid + i * 256;
        float u = xr[idx];
        v[i] = u; s += u; s2 += u * u;
    }
    {                                       // idx 1024..1151 -> r_feat
        int idx = tid + 1024;
        float u = (idx < K1c) ? rr[idx - Dc] : 0.f;
        v[4] = u; s += u; s2 += u * u;
    }
    __shared__ float red[8];
    float sw = wave_red_sum(s), s2w = wave_red_sum(s2);
    if (lane == 0) { red[wave] = sw; red[4 + wave] = s2w; }
    __syncthreads();
    float stot  = red[0] + red[1] + red[2] + red[3];
    float s2tot = red[4] + red[5] + red[6] + red[7];
    const float inv = 1.0f / (float)K1c;
    float mu = stot * inv;
    float var = s2tot * inv - mu * mu;
    float rstd = rsqrtf(var + EPSc);

    __hip_bfloat16* orow = aln + (size_t)row * K1c;
    #pragma unroll
    for (int i = 0; i < 4; i++) {
        int idx = tid + i * 256;
        orow[idx] = __float2bfloat16((v[i] - mu) * rstd * g[idx] + b[idx]);
    }
    {
        int idx = tid + 1024;
        if (idx < K1c)
            orow[idx] = __float2bfloat16((v[4] - mu) * rstd * g[idx] + b[idx]);
    }
}

// ---------------- 128x128 bf16 MFMA GEMM (A [M][K], Bt [N][K]) --------------
// EPI==0: out = bf16( gelu(acc + bias[col]) )      (h matrix, row stride N)
// EPI==1: out = f32 ( acc + bias[col] + add[row*N+col] )
template <int EPI>
__global__ __launch_bounds__(256) void gemm128_kernel(
    const __hip_bfloat16* __restrict__ A, const __hip_bfloat16* __restrict__ Bt,
    int K, int N, const float* __restrict__ bias, const float* __restrict__ add,
    void* __restrict__ outp) {
    __shared__ __hip_bfloat16 As[128 * 64];
    __shared__ __hip_bfloat16 Bs[128 * 64];
    const int tid  = threadIdx.x;
    const int lane = tid & 63;
    const int wave = tid >> 6;
    const int wr = wave >> 1, wc = wave & 1;
    const int m0 = blockIdx.y * 128;
    const int n0 = blockIdx.x * 128;

    f32x4 acc[4][4] = {};

    for (int k0 = 0; k0 < K; k0 += 64) {
        __syncthreads();   // previous iter's LDS reads done
        #pragma unroll
        for (int i = 0; i < 4; i++) {
            int f = i * 256 + tid;
            int r = f >> 3, c8 = (f & 7) << 3;
            __builtin_amdgcn_global_load_lds(
                (const __attribute__((address_space(1))) void*)(A + (size_t)(m0 + r) * K + k0 + c8),
                (__attribute__((address_space(3))) void*)(As + f * 8), 16, 0, 0);
        }
        #pragma unroll
        for (int i = 0; i < 4; i++) {
            int f = i * 256 + tid;
            int r = f >> 3, c8 = (f & 7) << 3;
            __builtin_amdgcn_global_load_lds(
                (const __attribute__((address_space(1))) void*)(Bt + (size_t)(n0 + r) * K + k0 + c8),
                (__attribute__((address_space(3))) void*)(Bs + f * 8), 16, 0, 0);
        }
        __syncthreads();   // implies vmcnt(0) drain

        #pragma unroll
        for (int kk = 0; kk < 2; kk++) {
            short8 af[4], bfr[4];
            #pragma unroll
            for (int m = 0; m < 4; m++)
                af[m] = *(const short8*)(As + (wr * 64 + m * 16 + (lane & 15)) * 64 + kk * 32 + (lane >> 4) * 8);
            #pragma unroll
            for (int n = 0; n < 4; n++)
                bfr[n] = *(const short8*)(Bs + (wc * 64 + n * 16 + (lane & 15)) * 64 + kk * 32 + (lane >> 4) * 8);
            #pragma unroll
            for (int m = 0; m < 4; m++)
                #pragma unroll
                for (int n = 0; n < 4; n++)
                    acc[m][n] = __builtin_amdgcn_mfma_f32_16x16x32_bf16(af[m], bfr[n], acc[m][n], 0, 0, 0);
        }
    }

    // epilogue: C/D layout col = lane&15, row = (lane>>4)*4 + i
    #pragma unroll
    for (int m = 0; m < 4; m++) {
        int grow_base = m0 + wr * 64 + m * 16 + (lane >> 4) * 4;
        #pragma unroll
        for (int n = 0; n < 4; n++) {
            int gcol = n0 + wc * 64 + n * 16 + (lane & 15);
            float bv = bias[gcol];
            #pragma unroll
            for (int i = 0; i < 4; i++) {
                int grow = grow_base + i;
                float vv = acc[m][n][i] + bv;
                if (EPI == 0) {
                    ((__hip_bfloat16*)outp)[(size_t)grow * N + gcol] = __float2bfloat16(gelu_tanh(vv));
                } else {
                    ((float*)outp)[(size_t)grow * N + gcol] = vv + add[(size_t)grow * N + gcol];
                }
            }
        }
    }
}

// --------- fused path gating: LN(5120) -> 5 logits -> softmax -> mix --------
__global__ __launch_bounds__(256) void gate_kernel(
    const float* __restrict__ vtn, const float* __restrict__ dts,
    const float* __restrict__ g, const float* __restrict__ b,
    const float* __restrict__ gw, const float* __restrict__ gb,
    float* __restrict__ out, float* __restrict__ gmem) {
    int row = blockIdx.x;                       // b*T + t
    int tid = threadIdx.x, lane = tid & 63, wave = tid >> 6;
    __shared__ float z[ZDc];
    __shared__ float red[8];
    __shared__ float lsum[5];
    if (tid < 5) lsum[tid] = 0.f;

    float s = 0.f, s2 = 0.f;
    #pragma unroll
    for (int k = 0; k < ZDc / 256; k++) {
        int i = tid + k * 256;
        int p = i >> 10, d = i & 1023;
        float u = (p == 0) ? vtn[(size_t)row * Dc + d]
                           : dts[((size_t)(p - 1) * Mc + row) * Dc + d];
        z[i] = u; s += u; s2 += u * u;
    }
    float sw = wave_red_sum(s), s2w = wave_red_sum(s2);
    if (lane == 0) { red[wave] = sw; red[4 + wave] = s2w; }
    __syncthreads();
    float stot  = red[0] + red[1] + red[2] + red[3];
    float s2tot = red[4] + red[5] + red[6] + red[7];
    const float inv = 1.0f / (float)ZDc;
    float mu = stot * inv;
    float var = s2tot * inv - mu * mu;
    float rstd = rsqrtf(var + EPSc);

    // 5-logit GEMV over normalized z
    float lacc[5] = {0.f, 0.f, 0.f, 0.f, 0.f};
    #pragma unroll
    for (int k = 0; k < ZDc / 256; k++) {
        int i = tid + k * 256;
        float zh = (z[i] - mu) * rstd * g[i] + b[i];
        #pragma unroll
        for (int j = 0; j < 5; j++) lacc[j] += zh * gw[i * 5 + j];
    }
    #pragma unroll
    for (int j = 0; j < 5; j++) {
        float v = wave_red_sum(lacc[j]);
        if (lane == 0) atomicAdd(&lsum[j], v);
    }
    __syncthreads();

    float lg[5];
    #pragma unroll
    for (int j = 0; j < 5; j++) lg[j] = lsum[j] + gb[j];
    float mx = lg[0];
    #pragma unroll
    for (int j = 1; j < 5; j++) mx = fmaxf(mx, lg[j]);
    float ex[5], den = 0.f;
    #pragma unroll
    for (int j = 0; j < 5; j++) { ex[j] = expf(lg[j] - mx); den += ex[j]; }
    float rden = 1.0f / den;
    float pi[5];
    #pragma unroll
    for (int j = 0; j < 5; j++) pi[j] = ex[j] * rden;

    // out[d] = sum_p pi[p] * paths[p][d]
    #pragma unroll
    for (int k = 0; k < Dc / 256; k++) {
        int d = tid + k * 256;
        float o = 0.f;
        #pragma unroll
        for (int p = 0; p < 5; p++) o += pi[p] * z[p * Dc + d];
        out[(size_t)row * Dc + d] = o;
    }
    if (tid == 0) gmem[row] = pi[1] + pi[2] + pi[3] + pi[4];
}

extern "C" void kernel_launch(void* const* d_in, const int* in_sizes, int n_in,
                              void* d_out, int out_size, void* d_ws, size_t ws_size,
                              hipStream_t stream) {
    const float* x    = (const float*)d_in[0];
    const float* vt   = (const float*)d_in[1];
    const float* dts  = (const float*)d_in[2];
    const float* rf   = (const float*)d_in[3];
    const float* flg  = (const float*)d_in[4];
    const float* flb  = (const float*)d_in[5];
    const float* w1   = (const float*)d_in[6];
    const float* b1   = (const float*)d_in[7];
    const float* w2   = (const float*)d_in[8];
    const float* b2   = (const float*)d_in[9];
    const float* plg  = (const float*)d_in[10];
    const float* plb  = (const float*)d_in[11];
    const float* gw   = (const float*)d_in[12];
    const float* gb   = (const float*)d_in[13];

    char* ws = (char*)d_ws;
    size_t off = 0;
    __hip_bfloat16* w1t = (__hip_bfloat16*)(ws + off); off += (size_t)Hc * K1c * 2;   //  9.4 MB
    __hip_bfloat16* w2t = (__hip_bfloat16*)(ws + off); off += (size_t)Dc * Hc * 2;    //  8.4 MB
    __hip_bfloat16* aln = (__hip_bfloat16*)(ws + off); off += (size_t)Mc * K1c * 2;   // 18.9 MB
    __hip_bfloat16* h   = (__hip_bfloat16*)(ws + off); off += (size_t)Mc * Hc * 2;    // 67.1 MB
    float*          vtn = (float*)(ws + off);          off += (size_t)Mc * Dc * 4;    // 33.6 MB

    // 1,2: weight transpose+cast -> [N][K] bf16
    transpose_cast_kernel<<<dim3(Hc / 32, K1c / 32), dim3(32, 8), 0, stream>>>(w1, w1t, K1c, Hc);
    transpose_cast_kernel<<<dim3(Dc / 32, Hc / 32), dim3(32, 8), 0, stream>>>(w2, w2t, Hc, Dc);

    // 3: fused concat + LN -> bf16 A
    fuse_ln_kernel<<<Mc, 256, 0, stream>>>(x, rf, flg, flb, aln);

    // 4: h = gelu(A @ w1 + b1)  -> bf16 [M][H]
    gemm128_kernel<0><<<dim3(Hc / 128, Mc / 128), 256, 0, stream>>>(aln, w1t, K1c, Hc, b1, nullptr, h);

    // 5: vt_new = vt + h @ w2 + b2 -> f32 [M][D]
    gemm128_kernel<1><<<dim3(Dc / 128, Mc / 128), 256, 0, stream>>>(h, w2t, Hc, Dc, b2, vt, vtn);

    // 6: gating + mix -> out, g_mem
    float* outp = (float*)d_out;
    gate_kernel<<<Mc, 256, 0, stream>>>(vtn, dts, plg, plb, gw, gb, outp, outp + (size_t)Mc * Dc);
}